// Round 5
// baseline (4287.818 us; speedup 1.0000x reference)
//
#include <hip/hip_runtime.h>
#include <hip/hip_bf16.h>

#define DIM    512
#define HEADS  8
#define DHD    64
#define MLAND  256
#define NTOK   10001
#define NPATCH 10000
#define NPAD   10240
#define PADR   239
#define LFAC   40
#define QKVLD  1536
#define PSTR   10048
#define MOUT   10112

typedef __bf16 bf16x8_t __attribute__((ext_vector_type(8)));
typedef float  f32x4_t  __attribute__((ext_vector_type(4)));
typedef short  short8_t __attribute__((ext_vector_type(8)));

__device__ inline bf16x8_t bzero8() {
    union { short8_t s; bf16x8_t b; } u;
    u.s = (short8_t){0, 0, 0, 0, 0, 0, 0, 0};
    return u.b;
}

// ---------------------------------------------------------------- concat
__global__ void k_concat(const float* __restrict__ x, const float* __restrict__ cls,
                         float* __restrict__ h) {
    int idx = blockIdx.x * 256 + threadIdx.x;
    if (idx >= NTOK * DIM) return;
    int row = idx / DIM, col = idx % DIM;
    h[idx] = (row == 0) ? cls[col] : x[(row - 1) * DIM + col];
}

// ---------------------------------------------------------------- layernorm -> bf16 padded A
__global__ void k_layernorm_bf(const float* __restrict__ h, const float* __restrict__ w,
                               const float* __restrict__ b, __hip_bfloat16* __restrict__ xbf) {
    int row = blockIdx.x;
    const float* r = h + (long)row * DIM;
    int t = threadIdx.x;
    float v0 = r[t], v1 = r[t + 256];
    __shared__ float red[256];
    red[t] = v0 + v1; __syncthreads();
    for (int o = 128; o > 0; o >>= 1) { if (t < o) red[t] += red[t + o]; __syncthreads(); }
    float mu = red[0] * (1.f / DIM); __syncthreads();
    float d0 = v0 - mu, d1 = v1 - mu;
    red[t] = d0 * d0 + d1 * d1; __syncthreads();
    for (int o = 128; o > 0; o >>= 1) { if (t < o) red[t] += red[t + o]; __syncthreads(); }
    float rstd = rsqrtf(red[0] * (1.f / DIM) + 1e-5f);
    long base = (long)(PADR + row) * DIM;
    xbf[base + t]       = __float2bfloat16(d0 * rstd * w[t] + b[t]);
    xbf[base + t + 256] = __float2bfloat16(d1 * rstd * w[t + 256] + b[t + 256]);
}

// ---------------------------------------------------------------- helpers
__global__ void k_zero(float* __restrict__ p, int n) {
    int i = blockIdx.x * 256 + threadIdx.x;
    if (i < n) p[i] = 0.f;
}
__global__ void k_zerobf(__hip_bfloat16* __restrict__ p, int n) {
    int i = blockIdx.x * 256 + threadIdx.x;
    if (i < n) p[i] = __float2bfloat16(0.f);
}
__global__ void k_cvt(const float* __restrict__ s, __hip_bfloat16* __restrict__ d, int n) {
    int i = blockIdx.x * 256 + threadIdx.x;
    if (i < n) d[i] = __float2bfloat16(s[i]);
}
__global__ void k_cvt_pad(const float* __restrict__ s, __hip_bfloat16* __restrict__ d,
                          int rows_src, int rows_dst, int cols) {
    int i = blockIdx.x * 256 + threadIdx.x;
    if (i >= rows_dst * cols) return;
    int row = i / cols;
    d[i] = __float2bfloat16(row < rows_src ? s[i] : 0.f);
}
__global__ void k_wt_cvt(const float* __restrict__ W, __hip_bfloat16* __restrict__ Wt,
                         int K, int N) {
    __shared__ float tile[32][33];
    int k0 = blockIdx.x * 32, n0 = blockIdx.y * 32;
    int lx = threadIdx.x % 32, ly = threadIdx.x / 32;
    for (int i = 0; i < 32; i += 8) tile[ly + i][lx] = W[(long)(k0 + ly + i) * N + n0 + lx];
    __syncthreads();
    for (int i = 0; i < 32; i += 8)
        Wt[(long)(n0 + ly + i) * K + k0 + lx] = __float2bfloat16(tile[lx][ly + i]);
}
// v slice of qkvbf -> vt bf16 [c][n]
__global__ void k_vt(const __hip_bfloat16* __restrict__ qkvbf, __hip_bfloat16* __restrict__ vt) {
    __shared__ __hip_bfloat16 tile[32][33];
    int n0 = blockIdx.x * 32, c0 = blockIdx.y * 32;
    int lx = threadIdx.x % 32, ly = threadIdx.x / 32;
    for (int i = 0; i < 32; i += 8)
        tile[ly + i][lx] = qkvbf[(long)(n0 + ly + i) * QKVLD + 1024 + c0 + lx];
    __syncthreads();
    for (int i = 0; i < 32; i += 8)
        vt[(long)(c0 + ly + i) * NPAD + n0 + lx] = tile[lx][ly + i];
}
// a3v fp32 [h][256][64] -> a3vt bf16 [h][64][256]
__global__ void k_a3vt(const float* __restrict__ a3v, __hip_bfloat16* __restrict__ a3vt) {
    __shared__ float tile[32][33];
    int h = blockIdx.z;
    int d0 = blockIdx.x * 32, m0 = blockIdx.y * 32;
    long base = (long)h * 16384;
    int lx = threadIdx.x % 32, ly = threadIdx.x / 32;
    for (int i = 0; i < 32; i += 8)
        tile[ly + i][lx] = a3v[base + (long)(m0 + ly + i) * 64 + d0 + lx];
    __syncthreads();
    for (int i = 0; i < 32; i += 8)
        a3vt[base + (long)(d0 + ly + i) * 256 + m0 + lx] = __float2bfloat16(tile[lx][ly + i]);
}

// ---------------------------------------------------------------- MFMA GEMM 128x128 (LDS-staged), optional fp32/bf16 out
__global__ __launch_bounds__(256) void k_mfma_gemm(
    const __hip_bfloat16* __restrict__ A, const __hip_bfloat16* __restrict__ Bt,
    float* __restrict__ C, int M, int N, int K, int Mstore,
    int scale_cols, float scale_val, const float* __restrict__ bias, int accum,
    __hip_bfloat16* __restrict__ Cbf)
{
    __shared__ unsigned short As[128 * 40];
    __shared__ unsigned short Bs[128 * 40];
    int tid = threadIdx.x;
    int m0 = blockIdx.y * 128, n0 = blockIdx.x * 128;
    int wave = tid >> 6, lane = tid & 63;
    int wm = (wave & 1) * 64, wn = (wave >> 1) * 64;
    f32x4_t zero4 = {0.f, 0.f, 0.f, 0.f};
    f32x4_t acc[4][4];
#pragma unroll
    for (int i = 0; i < 4; i++)
#pragma unroll
        for (int j = 0; j < 4; j++) acc[i][j] = zero4;
    int srow = tid >> 2, skc = (tid & 3) * 8;
    int quad = lane >> 4, fr = lane & 15;

    for (int k0 = 0; k0 < K; k0 += 32) {
        uint4 av0 = *(const uint4*)(A + (long)(m0 + srow) * K + k0 + skc);
        uint4 av1 = *(const uint4*)(A + (long)(m0 + srow + 64) * K + k0 + skc);
        uint4 bv0 = *(const uint4*)(Bt + (long)(n0 + srow) * K + k0 + skc);
        uint4 bv1 = *(const uint4*)(Bt + (long)(n0 + srow + 64) * K + k0 + skc);
        __syncthreads();
        *(uint4*)&As[srow * 40 + skc] = av0;
        *(uint4*)&As[(srow + 64) * 40 + skc] = av1;
        *(uint4*)&Bs[srow * 40 + skc] = bv0;
        *(uint4*)&Bs[(srow + 64) * 40 + skc] = bv1;
        __syncthreads();
        bf16x8_t af[4], bq[4];
#pragma unroll
        for (int i = 0; i < 4; i++) {
            af[i] = *(const bf16x8_t*)&As[(wm + i * 16 + fr) * 40 + quad * 8];
            bq[i] = *(const bf16x8_t*)&Bs[(wn + i * 16 + fr) * 40 + quad * 8];
        }
#pragma unroll
        for (int i = 0; i < 4; i++)
#pragma unroll
            for (int j = 0; j < 4; j++)
                acc[i][j] = __builtin_amdgcn_mfma_f32_16x16x32_bf16(af[i], bq[j], acc[i][j], 0, 0, 0);
    }
    int col = lane & 15, rq = lane >> 4;
#pragma unroll
    for (int j = 0; j < 4; j++) {
        int c = n0 + wn + j * 16 + col;
        float bsv = bias ? bias[c] : 0.f;
        float sc = (c < scale_cols) ? scale_val : 1.f;
#pragma unroll
        for (int i = 0; i < 4; i++) {
            int rbase = m0 + wm + i * 16 + rq * 4;
#pragma unroll
            for (int rr = 0; rr < 4; rr++) {
                int r = rbase + rr;
                if (r >= Mstore) continue;
                float v = acc[i][j][rr] * sc + bsv;
                long off = (long)r * N + c;
                if (C) { if (accum) C[off] += v; else C[off] = v; }
                if (Cbf) Cbf[off] = __float2bfloat16(v);
            }
        }
    }
}

// ---------------------------------------------------------------- generic MFMA NT scores kernel, 128x128, no LDS
__global__ __launch_bounds__(256) void k_mfma_nt(
    const __hip_bfloat16* __restrict__ A, long lda, long abatch, int arowmax,
    const __hip_bfloat16* __restrict__ Bt, long ldb, long bbatch,
    float* __restrict__ C, long ldc, long cbatch, int crowmax, int K)
{
    int h = blockIdx.z;
    const __hip_bfloat16* Ab = A + (long)h * abatch;
    const __hip_bfloat16* Bb = Bt + (long)h * bbatch;
    float* Cb = C + (long)h * cbatch;
    int m0 = blockIdx.y * 128, n0 = blockIdx.x * 128;
    int wave = threadIdx.x >> 6, lane = threadIdx.x & 63;
    int wm = (wave & 1) * 64, wn = (wave >> 1) * 64;
    int fr = lane & 15, quad = lane >> 4;
    f32x4_t zero4 = {0.f, 0.f, 0.f, 0.f};
    f32x4_t acc[4][4];
#pragma unroll
    for (int i = 0; i < 4; i++)
#pragma unroll
        for (int j = 0; j < 4; j++) acc[i][j] = zero4;
    for (int k0 = 0; k0 < K; k0 += 32) {
        bf16x8_t af[4], bq[4];
#pragma unroll
        for (int i = 0; i < 4; i++) {
            int r = m0 + wm + i * 16 + fr;
            af[i] = (r < arowmax) ? *(const bf16x8_t*)(Ab + (long)r * lda + k0 + quad * 8)
                                  : bzero8();
        }
#pragma unroll
        for (int j = 0; j < 4; j++) {
            int n = n0 + wn + j * 16 + fr;
            bq[j] = *(const bf16x8_t*)(Bb + (long)n * ldb + k0 + quad * 8);
        }
#pragma unroll
        for (int i = 0; i < 4; i++)
#pragma unroll
            for (int j = 0; j < 4; j++)
                acc[i][j] = __builtin_amdgcn_mfma_f32_16x16x32_bf16(af[i], bq[j], acc[i][j], 0, 0, 0);
    }
#pragma unroll
    for (int i = 0; i < 4; i++)
#pragma unroll
        for (int j = 0; j < 4; j++)
#pragma unroll
            for (int rr = 0; rr < 4; rr++) {
                int r = m0 + wm + i * 16 + quad * 4 + rr;
                int c = n0 + wn + j * 16 + fr;
                if (r < crowmax) Cb[(long)r * ldc + c] = acc[i][j][rr];
            }
}

// ---------------------------------------------------------------- generic MFMA 128x64 tile, split-K / accum / bf16-T out
// mode 0: atomicAdd fp32; mode 1: fp32 +=; mode 2: bf16 transposed store
__global__ __launch_bounds__(256) void k_mfma_t64(
    const __hip_bfloat16* __restrict__ A, long lda, long abatch, int arowmax,
    const __hip_bfloat16* __restrict__ Bt, long ldb, long bbatch,
    float* __restrict__ Cf, __hip_bfloat16* __restrict__ Cbf,
    long ldc, long cbatch, int crowmax, int ksplit, int mode)
{
    int h = blockIdx.z;
    const __hip_bfloat16* Ab = A + (long)h * abatch;
    const __hip_bfloat16* Bb = Bt + (long)h * bbatch;
    int m0 = blockIdx.y * 128;
    int kbeg = blockIdx.x * ksplit, kend = kbeg + ksplit;
    int wave = threadIdx.x >> 6, lane = threadIdx.x & 63;
    int wm = (wave & 1) * 64, wn = (wave >> 1) * 32;
    int fr = lane & 15, quad = lane >> 4;
    f32x4_t zero4 = {0.f, 0.f, 0.f, 0.f};
    f32x4_t acc[4][2];
#pragma unroll
    for (int i = 0; i < 4; i++) { acc[i][0] = zero4; acc[i][1] = zero4; }
    for (int k0 = kbeg; k0 < kend; k0 += 32) {
        bf16x8_t bq[2];
#pragma unroll
        for (int j = 0; j < 2; j++)
            bq[j] = *(const bf16x8_t*)(Bb + (long)(wn + j * 16 + fr) * ldb + k0 + quad * 8);
#pragma unroll
        for (int i = 0; i < 4; i++) {
            int r = m0 + wm + i * 16 + fr;
            bf16x8_t af = (r < arowmax) ? *(const bf16x8_t*)(Ab + (long)r * lda + k0 + quad * 8)
                                        : bzero8();
#pragma unroll
            for (int j = 0; j < 2; j++)
                acc[i][j] = __builtin_amdgcn_mfma_f32_16x16x32_bf16(af, bq[j], acc[i][j], 0, 0, 0);
        }
    }
#pragma unroll
    for (int i = 0; i < 4; i++)
#pragma unroll
        for (int j = 0; j < 2; j++)
#pragma unroll
            for (int rr = 0; rr < 4; rr++) {
                int r = m0 + wm + i * 16 + quad * 4 + rr;
                int c = wn + j * 16 + fr;
                float v = acc[i][j][rr];
                if (mode == 0) {
                    atomicAdd(Cf + (long)h * cbatch + (long)r * ldc + c, v);
                } else if (mode == 1) {
                    if (r < crowmax) Cf[(long)h * cbatch + (long)r * ldc + c] += v;
                } else {
                    Cbf[(long)h * cbatch + (long)c * ldc + r] = __float2bfloat16(v);
                }
            }
}

// ---------------------------------------------------------------- persistent per-head pinv: one block per head,
// 8 waves, each wave a 64x128 region; __threadfence+__syncthreads between the 24 dependent phases.
__global__ __launch_bounds__(512) void k_pinv(
    const __hip_bfloat16* __restrict__ x2a,
    __hip_bfloat16* za,  __hip_bfloat16* zt,
    __hip_bfloat16* za2, __hip_bfloat16* zt2,
    __hip_bfloat16* xza, __hip_bfloat16* xzt,
    __hip_bfloat16* t1t, __hip_bfloat16* t2t)
{
    int hd = blockIdx.x;
    long hb = (long)hd * 65536;
    int wave = threadIdx.x >> 6, lane = threadIdx.x & 63;
    int m0 = (wave >> 1) * 64;
    int n0w = (wave & 1) * 128;
    int fr = lane & 15, quad = lane >> 4;
    f32x4_t zero4 = {0.f, 0.f, 0.f, 0.f};

    auto mm = [&](const __hip_bfloat16* A, const __hip_bfloat16* Bt,
                  float s, float ac, const __hip_bfloat16* Aadd,
                  __hip_bfloat16* Crow, __hip_bfloat16* Ct) {
        f32x4_t acc[4][8];
#pragma unroll
        for (int i = 0; i < 4; i++)
#pragma unroll
            for (int j = 0; j < 8; j++) acc[i][j] = zero4;
#pragma unroll
        for (int k0 = 0; k0 < 256; k0 += 32) {
            bf16x8_t af[4], bq[8];
#pragma unroll
            for (int i = 0; i < 4; i++)
                af[i] = *(const bf16x8_t*)(A + hb + (long)(m0 + i * 16 + fr) * 256 + k0 + quad * 8);
#pragma unroll
            for (int j = 0; j < 8; j++)
                bq[j] = *(const bf16x8_t*)(Bt + hb + (long)(n0w + j * 16 + fr) * 256 + k0 + quad * 8);
#pragma unroll
            for (int i = 0; i < 4; i++)
#pragma unroll
                for (int j = 0; j < 8; j++)
                    acc[i][j] = __builtin_amdgcn_mfma_f32_16x16x32_bf16(af[i], bq[j], acc[i][j], 0, 0, 0);
        }
#pragma unroll
        for (int i = 0; i < 4; i++)
#pragma unroll
            for (int j = 0; j < 8; j++)
#pragma unroll
                for (int rr = 0; rr < 4; rr++) {
                    int r = m0 + i * 16 + quad * 4 + rr;
                    int c = n0w + j * 16 + fr;
                    float v = s * acc[i][j][rr];
                    if (Aadd) v += ac * __bfloat162float(Aadd[hb + (long)r * 256 + c]);
                    __hip_bfloat16 bv = __float2bfloat16(v);
                    if (Crow) Crow[hb + (long)r * 256 + c] = bv;
                    if (Ct)   Ct[hb + (long)c * 256 + r] = bv;
                }
        __threadfence();
        __syncthreads();
    };

    __hip_bfloat16 *zra = za, *zrt = zt, *zoa = za2, *zot = zt2;
    for (int it = 0; it < 6; it++) {
        mm(x2a, zrt, 1.f, 0.f, nullptr, xza, xzt);
        mm(xza, xzt, -1.f, 7.f, xza, nullptr, t1t);
        mm(xza, t1t, -1.f, 15.f, xza, nullptr, t2t);
        mm(zra, t2t, -0.25f, 3.25f, zra, zoa, zot);
        __hip_bfloat16* tmp;
        tmp = zra; zra = zoa; zoa = tmp;
        tmp = zrt; zrt = zot; zot = tmp;
    }
    // final z row-major bf16 ends in za (6 swaps)
}

// ---------------------------------------------------------------- landmark means (bf16 in; fp32 + bf16 out)
__global__ void k_landmarks(const __hip_bfloat16* __restrict__ qkvbf, float* __restrict__ ql,
                            float* __restrict__ kl, __hip_bfloat16* __restrict__ qlbf,
                            __hip_bfloat16* __restrict__ klbf) {
    int m = blockIdx.x, h = blockIdx.y, d = threadIdx.x;
    float sq = 0.f, sk = 0.f;
    for (int j = 0; j < LFAC; j++) {
        long base = (long)(m * LFAC + j) * QKVLD + h * DHD + d;
        sq += __bfloat162float(qkvbf[base]);
        sk += __bfloat162float(qkvbf[base + 512]);
    }
    long o = ((long)h * MLAND + m) * DHD + d;
    float vq = sq * (1.f / LFAC), vk = sk * (1.f / LFAC);
    ql[o] = vq; kl[o] = vk;
    qlbf[o] = __float2bfloat16(vq);
    klbf[o] = __float2bfloat16(vk);
}

// ---------------------------------------------------------------- attn2 = softmax(q_l @ k_l^T) fp32
__global__ void k_attn2(const float* __restrict__ ql, const float* __restrict__ kl,
                        float* __restrict__ attn2) {
    int i = blockIdx.x, h = blockIdx.y, j = threadIdx.x;
    __shared__ float q[64];
    __shared__ float red[256];
    if (j < 64) q[j] = ql[((long)h * MLAND + i) * DHD + j];
    __syncthreads();
    const float* kr = kl + ((long)h * MLAND + j) * DHD;
    float s = 0.f;
#pragma unroll 8
    for (int d = 0; d < 64; d++) s += q[d] * kr[d];
    red[j] = s; __syncthreads();
    for (int o = 128; o > 0; o >>= 1) { if (j < o) red[j] = fmaxf(red[j], red[j + o]); __syncthreads(); }
    float mx = red[0]; __syncthreads();
    float e = __expf(s - mx);
    red[j] = e; __syncthreads();
    for (int o = 128; o > 0; o >>= 1) { if (j < o) red[j] += red[j + o]; __syncthreads(); }
    attn2[((long)h * MLAND + i) * MLAND + j] = e / red[0];
}

// ---------------------------------------------------------------- pinv scale: max |row/col sums|
__global__ void k_colrow(const float* __restrict__ x, float* __restrict__ scal) {
    int h = blockIdx.x, t = threadIdx.x;
    const float* xh = x + (long)h * MLAND * MLAND;
    float cs = 0.f, rs = 0.f;
    for (int j = 0; j < MLAND; j++) {
        cs += fabsf(xh[(long)t * MLAND + j]);
        rs += fabsf(xh[(long)j * MLAND + t]);
    }
    __shared__ float red[256];
    red[t] = cs; __syncthreads();
    for (int o = 128; o > 0; o >>= 1) { if (t < o) red[t] = fmaxf(red[t], red[t + o]); __syncthreads(); }
    if (t == 0) atomicMax((int*)&scal[0], __float_as_int(red[0]));
    __syncthreads();
    red[t] = rs; __syncthreads();
    for (int o = 128; o > 0; o >>= 1) { if (t < o) red[t] = fmaxf(red[t], red[t + o]); __syncthreads(); }
    if (t == 0) atomicMax((int*)&scal[1], __float_as_int(red[0]));
}

// ---------------------------------------------------------------- z0 init (za = x^T*inv, zt = x*inv)
__global__ void k_tscale2(const float* __restrict__ x, const float* __restrict__ scal,
                          __hip_bfloat16* __restrict__ za, __hip_bfloat16* __restrict__ zt) {
    int h = blockIdx.z;
    int tj = blockIdx.x * 32, ti = blockIdx.y * 32;
    __shared__ float tile[32][33];
    const float* xh = x + (long)h * 65536;
    int lx = threadIdx.x % 32, ly = threadIdx.x / 32;
    float inv = 1.f / (scal[0] * scal[1]);
    for (int yy = 0; yy < 32; yy += 8) {
        float v = xh[(long)(ti + ly + yy) * MLAND + tj + lx];
        tile[ly + yy][lx] = v;
        zt[(long)h * 65536 + (long)(ti + ly + yy) * MLAND + tj + lx] = __float2bfloat16(v * inv);
    }
    __syncthreads();
    for (int yy = 0; yy < 32; yy += 8)
        za[(long)h * 65536 + (long)(tj + ly + yy) * MLAND + ti + lx] =
            __float2bfloat16(tile[lx][ly + yy] * inv);
}

// ---------------------------------------------------------------- softmax over 10240, in-place bf16 out (first half of row)
__global__ __launch_bounds__(256) void k_softmax3(float* S) {
    long row = blockIdx.x;
    float* r = S + row * NPAD;
    __hip_bfloat16* ob = (__hip_bfloat16*)S + row * (2L * NPAD);
    int t = threadIdx.x;
    float v[40];
    float mx = -1e30f;
#pragma unroll
    for (int j = 0; j < 40; j++) { v[j] = r[t + j * 256]; mx = fmaxf(mx, v[j]); }
    __shared__ float red[256];
    red[t] = mx; __syncthreads();
    for (int o = 128; o > 0; o >>= 1) { if (t < o) red[t] = fmaxf(red[t], red[t + o]); __syncthreads(); }
    mx = red[0]; __syncthreads();
    float s = 0.f;
#pragma unroll
    for (int j = 0; j < 40; j++) { v[j] = __expf(v[j] - mx); s += v[j]; }
    red[t] = s; __syncthreads();
    for (int o = 128; o > 0; o >>= 1) { if (t < o) red[t] += red[t + o]; __syncthreads(); }
    float inv = 1.f / red[0];
#pragma unroll
    for (int j = 0; j < 40; j++) ob[t + j * 256] = __float2bfloat16(v[j] * inv);
}

// ---------------------------------------------------------------- softmax over 256 (attn1), in-place bf16 out
__global__ void k_softmax1(float* S) {
    int h = blockIdx.y;
    int i = blockIdx.x * 4 + (threadIdx.x >> 6);
    if (i >= NTOK) return;
    int lane = threadIdx.x & 63;
    const float* r = S + ((long)h * PSTR + i) * MLAND + lane * 4;
    float4 v = *(const float4*)r;
    float mx = fmaxf(fmaxf(v.x, v.y), fmaxf(v.z, v.w));
#pragma unroll
    for (int o = 32; o > 0; o >>= 1) mx = fmaxf(mx, __shfl_xor(mx, o));
    float e0 = __expf(v.x - mx), e1 = __expf(v.y - mx);
    float e2 = __expf(v.z - mx), e3 = __expf(v.w - mx);
    float s = e0 + e1 + e2 + e3;
#pragma unroll
    for (int o = 32; o > 0; o >>= 1) s += __shfl_xor(s, o);
    float inv = 1.f / s;
    __hip_bfloat16* ob = (__hip_bfloat16*)S + ((long)h * PSTR + i) * 512L + lane * 4;
    ob[0] = __float2bfloat16(e0 * inv);
    ob[1] = __float2bfloat16(e1 * inv);
    ob[2] = __float2bfloat16(e2 * inv);
    ob[3] = __float2bfloat16(e3 * inv);
}

// ---------------------------------------------------------------- conv residual -> aout (bf16 v)
__global__ void k_conv_res(const __hip_bfloat16* __restrict__ qkvbf, const float* __restrict__ resw,
                           float* __restrict__ aout) {
    int e = blockIdx.x * 256 + threadIdx.x;
    if (e >= NTOK * DIM) return;
    int i = e >> 9, c = e & 511;
    int hh = c >> 6;
    int n = PADR + i;
    float acc = 0.f;
#pragma unroll
    for (int t = 0; t < 33; t++) {
        int nn = n - 16 + t;
        if (nn < NPAD)
            acc += resw[hh * 33 + t] * __bfloat162float(qkvbf[(long)nn * QKVLD + 1024 + c]);
    }
    aout[e] = acc;
}

// ---------------------------------------------------------------- ppeg transposes + combined 49-tap conv
__global__ void k_tfwd(const float* __restrict__ h, float* __restrict__ ft) {
    __shared__ float tile[32][33];
    int t0 = blockIdx.x * 32, c0 = blockIdx.y * 32;
    int lx = threadIdx.x % 32, ly = threadIdx.x / 32;
    for (int i = 0; i < 32; i += 8) {
        int t = t0 + ly + i;
        if (t < NPATCH) tile[ly + i][lx] = h[(long)(1 + t) * DIM + c0 + lx];
    }
    __syncthreads();
    for (int i = 0; i < 32; i += 8) {
        int c = c0 + ly + i, t = t0 + lx;
        if (t < NPATCH) ft[(long)c * NPATCH + t] = tile[lx][ly + i];
    }
}

__global__ __launch_bounds__(256) void k_ppeg2(
    const float* __restrict__ ft, float* __restrict__ yt,
    const float* __restrict__ w7, const float* __restrict__ b7,
    const float* __restrict__ w5, const float* __restrict__ b5,
    const float* __restrict__ w3, const float* __restrict__ b3)
{
    int s = blockIdx.x, c = blockIdx.y;
    __shared__ float tile[26][106];
    __shared__ float wt[49];
    int tid = threadIdx.x;
    int r0 = s * 20 - 3;
    for (int idx = tid; idx < 26 * 106; idx += 256) {
        int rr = idx / 106, cc = idx % 106;
        int gy = r0 + rr, gx = cc - 3;
        float v = 0.f;
        if (gy >= 0 && gy < 100 && gx >= 0 && gx < 100)
            v = ft[(long)c * NPATCH + gy * 100 + gx];
        tile[rr][cc] = v;
    }
    if (tid < 49) {
        int dy = tid / 7 - 3, dx = tid % 7 - 3;
        float w = w7[c * 49 + tid];
        if (dy >= -2 && dy <= 2 && dx >= -2 && dx <= 2) w += w5[c * 25 + (dy + 2) * 5 + (dx + 2)];
        if (dy >= -1 && dy <= 1 && dx >= -1 && dx <= 1) w += w3[c * 9 + (dy + 1) * 3 + (dx + 1)];
        wt[tid] = w;
    }
    __syncthreads();
    float bsum = b7[c] + b5[c] + b3[c];
    for (int p = tid; p < 2000; p += 256) {
        int ly = p / 100, lx = p % 100;
        float acc = tile[ly + 3][lx + 3] + bsum;
#pragma unroll
        for (int dy = 0; dy < 7; dy++)
#pragma unroll
            for (int dx = 0; dx < 7; dx++)
                acc += wt[dy * 7 + dx] * tile[ly + dy][lx + dx];
        yt[(long)c * NPATCH + (s * 20 + ly) * 100 + lx] = acc;
    }
}

__global__ void k_tback(const float* __restrict__ yt, float* __restrict__ h) {
    __shared__ float tile[32][33];
    int t0 = blockIdx.x * 32, c0 = blockIdx.y * 32;
    int lx = threadIdx.x % 32, ly = threadIdx.x / 32;
    for (int i = 0; i < 32; i += 8) {
        int c = c0 + ly + i, t = t0 + lx;
        if (t < NPATCH) tile[ly + i][lx] = yt[(long)c * NPATCH + t];
    }
    __syncthreads();
    for (int i = 0; i < 32; i += 8) {
        int t = t0 + ly + i;
        if (t < NPATCH) h[(long)(1 + t) * DIM + c0 + lx] = tile[lx][ly + i];
    }
}

// ---------------------------------------------------------------- final LN + heads + softmax
__global__ void k_final(const float* __restrict__ h, const float* __restrict__ nw,
                        const float* __restrict__ nb,
                        const float* __restrict__ fc2w, const float* __restrict__ fc2b,
                        const float* __restrict__ pcw, const float* __restrict__ pcb,
                        float* __restrict__ out)
{
    int row = blockIdx.x;
    int t = threadIdx.x;
    const float* r = h + (long)row * DIM;
    float v0 = r[t], v1 = r[t + 256];
    __shared__ float red[256];
    red[t] = v0 + v1; __syncthreads();
    for (int o = 128; o > 0; o >>= 1) { if (t < o) red[t] += red[t + o]; __syncthreads(); }
    float mu = red[0] * (1.f / DIM); __syncthreads();
    float d0 = v0 - mu, d1 = v1 - mu;
    red[t] = d0 * d0 + d1 * d1; __syncthreads();
    for (int o = 128; o > 0; o >>= 1) { if (t < o) red[t] += red[t + o]; __syncthreads(); }
    float rstd = rsqrtf(red[0] * (1.f / DIM) + 1e-5f); __syncthreads();
    float h0 = d0 * rstd * nw[t] + nb[t];
    float h1 = d1 * rstd * nw[t + 256] + nb[t + 256];
    const float* w = (row == 0) ? fc2w : pcw;
    float p0 = h0 * w[t * 2] + h1 * w[(t + 256) * 2];
    float p1 = h0 * w[t * 2 + 1] + h1 * w[(t + 256) * 2 + 1];
    red[t] = p0; __syncthreads();
    for (int o = 128; o > 0; o >>= 1) { if (t < o) red[t] += red[t + o]; __syncthreads(); }
    float l0 = red[0]; __syncthreads();
    red[t] = p1; __syncthreads();
    for (int o = 128; o > 0; o >>= 1) { if (t < o) red[t] += red[t + o]; __syncthreads(); }
    if (t == 0) {
        float l1 = red[0];
        const float* bb = (row == 0) ? fc2b : pcb;
        float a0 = l0 + bb[0], a1 = l1 + bb[1];
        if (row == 0) { out[0] = a0; out[1] = a1; }
        else {
            long i = row - 1;
            out[2 + i * 2] = a0;
            out[2 + i * 2 + 1] = a1;
            float m = fmaxf(a0, a1);
            float e0 = __expf(a0 - m), e1 = __expf(a1 - m);
            float inv = 1.f / (e0 + e1);
            out[2 + 2 * NPATCH + i * 2] = e0 * inv;
            out[2 + 2 * NPATCH + i * 2 + 1] = e1 * inv;
        }
    }
}

// ================================================================ launcher
extern "C" void kernel_launch(void* const* d_in, const int* in_sizes, int n_in,
                              void* d_out, int out_size, void* d_ws, size_t ws_size,
                              hipStream_t stream)
{
    const float* x     = (const float*)d_in[0];
    const float* cls   = (const float*)d_in[1];
    const float* ln1w  = (const float*)d_in[2];
    const float* ln1b  = (const float*)d_in[3];
    const float* qkv1w = (const float*)d_in[4];
    const float* out1w = (const float*)d_in[5];
    const float* out1b = (const float*)d_in[6];
    const float* res1w = (const float*)d_in[7];
    const float* p7w   = (const float*)d_in[8];
    const float* p7b   = (const float*)d_in[9];
    const float* p5w   = (const float*)d_in[10];
    const float* p5b   = (const float*)d_in[11];
    const float* p3w   = (const float*)d_in[12];
    const float* p3b   = (const float*)d_in[13];
    const float* ln2w  = (const float*)d_in[14];
    const float* ln2b  = (const float*)d_in[15];
    const float* qkv2w = (const float*)d_in[16];
    const float* out2w = (const float*)d_in[17];
    const float* out2b = (const float*)d_in[18];
    const float* res2w = (const float*)d_in[19];
    const float* normw = (const float*)d_in[20];
    const float* normb = (const float*)d_in[21];
    const float* fc2w  = (const float*)d_in[22];
    const float* fc2b  = (const float*)d_in[23];
    const float* pcw   = (const float*)d_in[24];
    const float* pcb   = (const float*)d_in[25];
    float* out = (float*)d_out;

    float* p = (float*)d_ws;
    float* h      = p; p += 5120512;     // 10001 x 512
    float* aout   = p; p += 5120512;     // 10001 x 512 (also ppeg yt)
    float* ql     = p; p += 131072;
    float* kl     = p; p += 131072;
    float* x2     = p; p += 524288;
    float* a3v    = p; p += 131072;
    float* scal   = p; p += 8;
    float* attn3f = p; p += 20971520;    // fp32 scores; softmax converts in-place to bf16; also aliases ft
    __hip_bfloat16* qkvbf = (__hip_bfloat16*)p; p += 7864320;   // 10240 x 1536
    __hip_bfloat16* xbf   = (__hip_bfloat16*)p; p += 2621440;   // 10240 x 512
    __hip_bfloat16* abf   = (__hip_bfloat16*)p; p += 2588672;   // 10112 x 512
    __hip_bfloat16* qw1t  = (__hip_bfloat16*)p; p += 393216;
    __hip_bfloat16* qw2t  = (__hip_bfloat16*)p; p += 393216;
    __hip_bfloat16* ow1t  = (__hip_bfloat16*)p; p += 131072;
    __hip_bfloat16* ow2t  = (__hip_bfloat16*)p; p += 131072;
    __hip_bfloat16* x2a   = (__hip_bfloat16*)p; p += 262144;
    __hip_bfloat16* za    = (__hip_bfloat16*)p; p += 262144;
    __hip_bfloat16* zt    = (__hip_bfloat16*)p; p += 262144;
    __hip_bfloat16* za2   = (__hip_bfloat16*)p; p += 262144;
    __hip_bfloat16* zt2   = (__hip_bfloat16*)p; p += 262144;
    __hip_bfloat16* xza   = (__hip_bfloat16*)p; p += 262144;
    __hip_bfloat16* xzt   = (__hip_bfloat16*)p; p += 262144;
    __hip_bfloat16* t1t   = (__hip_bfloat16*)p; p += 262144;
    __hip_bfloat16* t2t   = (__hip_bfloat16*)p; p += 262144;
    __hip_bfloat16* qlbf  = (__hip_bfloat16*)p; p += 65536;
    __hip_bfloat16* klbf  = (__hip_bfloat16*)p; p += 65536;
    __hip_bfloat16* vt    = (__hip_bfloat16*)p; p += 2621440;   // 8 x 64 x 10240
    __hip_bfloat16* a3vt  = (__hip_bfloat16*)p; p += 65536;
    __hip_bfloat16* w2bt  = (__hip_bfloat16*)p; p += 65536;
    float* ft = attn3f;   // ppeg channel-major buffer aliases dead score buffer
    float* yt = aout;

    k_concat<<<dim3((NTOK * DIM + 255) / 256), 256, 0, stream>>>(x, cls, h);
    k_wt_cvt<<<dim3(16, 48), 256, 0, stream>>>(qkv1w, qw1t, 512, 1536);
    k_wt_cvt<<<dim3(16, 48), 256, 0, stream>>>(qkv2w, qw2t, 512, 1536);
    k_wt_cvt<<<dim3(16, 16), 256, 0, stream>>>(out1w, ow1t, 512, 512);
    k_wt_cvt<<<dim3(16, 16), 256, 0, stream>>>(out2w, ow2t, 512, 512);
    k_zerobf<<<dim3((PADR * DIM + 255) / 256), 256, 0, stream>>>(xbf, PADR * DIM);

    auto layer = [&](const float* lnw, const float* lnb, const __hip_bfloat16* qwt,
                     const __hip_bfloat16* owt, const float* outb, const float* resw) {
        k_layernorm_bf<<<NTOK, 256, 0, stream>>>(h, lnw, lnb, xbf);
        k_mfma_gemm<<<dim3(12, 80), 256, 0, stream>>>(xbf, qwt, nullptr, NPAD, QKVLD, 512,
                                                      NPAD, 512, 0.125f, nullptr, 0, qkvbf);
        k_vt<<<dim3(320, 16), 256, 0, stream>>>(qkvbf, vt);
        k_landmarks<<<dim3(MLAND, HEADS), 64, 0, stream>>>(qkvbf, ql, kl, qlbf, klbf);
        k_attn2<<<dim3(MLAND, HEADS), 256, 0, stream>>>(ql, kl, x2);
        k_zero<<<1, 64, 0, stream>>>(scal, 8);
        k_colrow<<<HEADS, 256, 0, stream>>>(x2, scal);
        k_cvt<<<dim3(2048), 256, 0, stream>>>(x2, x2a, HEADS * 65536);
        k_tscale2<<<dim3(8, 8, HEADS), 256, 0, stream>>>(x2, scal, za, zt);
        k_pinv<<<HEADS, 512, 0, stream>>>(x2a, za, zt, za2, zt2, xza, xzt, t1t, t2t);
        // attn3: scores (MFMA) -> softmax (in-place bf16) -> @v (MFMA split-K)
        k_mfma_nt<<<dim3(80, 2, HEADS), 256, 0, stream>>>(
            qlbf, 64, 16384, 256, qkvbf + 512, QKVLD, 64,
            attn3f, NPAD, (long)256 * NPAD, 256, 64);
        k_softmax3<<<2048, 256, 0, stream>>>(attn3f);
        k_zero<<<512, 256, 0, stream>>>(a3v, 131072);
        k_mfma_t64<<<dim3(16, 2, HEADS), 256, 0, stream>>>(
            (__hip_bfloat16*)attn3f, 2L * NPAD, (long)256 * 2 * NPAD, 256,
            vt, NPAD, (long)64 * NPAD,
            a3v, nullptr, 64, 16384, 256, 640, 0);
        k_a3vt<<<dim3(2, 8, HEADS), 256, 0, stream>>>(a3v, a3vt);
        // w2b^T = (z @ a3v)^T bf16
        k_mfma_t64<<<dim3(1, 2, HEADS), 256, 0, stream>>>(
            za, 256, 65536, 256, a3vt, 256, 16384,
            nullptr, w2bt, 256, 16384, 256, 256, 2);
        // attn1: scores (MFMA) -> softmax (in-place bf16) -> conv residual -> +P@w2 (MFMA)
        k_mfma_nt<<<dim3(2, 79, HEADS), 256, 0, stream>>>(
            qkvbf + (long)PADR * QKVLD, QKVLD, 64, NTOK, klbf, 64, 16384,
            attn3f, 256, (long)PSTR * 256, NTOK, 64);
        k_softmax1<<<dim3(2501, HEADS), 256, 0, stream>>>(attn3f);
        k_conv_res<<<dim3((NTOK * DIM + 255) / 256), 256, 0, stream>>>(qkvbf, resw, aout);
        k_mfma_t64<<<dim3(1, 79, HEADS), 256, 0, stream>>>(
            (__hip_bfloat16*)attn3f, 512, (long)PSTR * 512, NTOK, w2bt, 256, 16384,
            aout, nullptr, 512, 64, NTOK, 256, 1);
        k_cvt_pad<<<dim3((MOUT * DIM + 255) / 256), 256, 0, stream>>>(aout, abf, NTOK, MOUT, DIM);
        k_mfma_gemm<<<dim3(4, 79), 256, 0, stream>>>(abf, owt, h, MOUT, 512, 512,
                                                     NTOK, 0, 0.f, outb, 1, nullptr);
    };

    layer(ln1w, ln1b, qw1t, ow1t, out1b, res1w);

    k_tfwd<<<dim3(313, 16), 256, 0, stream>>>(h, ft);
    k_ppeg2<<<dim3(5, 512), 256, 0, stream>>>(ft, yt, p7w, p7b, p5w, p5b, p3w, p3b);
    k_tback<<<dim3(313, 16), 256, 0, stream>>>(yt, h);

    layer(ln2w, ln2b, qw2t, ow2t, out2b, res2w);

    k_final<<<NTOK, 256, 0, stream>>>(h, normw, normb, fc2w, fc2b, pcw, pcb, out);
    (void)in_sizes; (void)n_in; (void)out_size; (void)ws_size;
}

// Round 6
// 2062.691 us; speedup vs baseline: 2.0787x; 2.0787x over previous
//
#include <hip/hip_runtime.h>
#include <hip/hip_bf16.h>

#define DIM    512
#define HEADS  8
#define DHD    64
#define MLAND  256
#define NTOK   10001
#define NPATCH 10000
#define NPAD   10240
#define PADR   239
#define LFAC   40
#define QKVLD  1536
#define PSTR   10048
#define MOUT   10112

typedef __bf16 bf16x8_t __attribute__((ext_vector_type(8)));
typedef float  f32x4_t  __attribute__((ext_vector_type(4)));
typedef short  short8_t __attribute__((ext_vector_type(8)));

__device__ inline bf16x8_t bzero8() {
    union { short8_t s; bf16x8_t b; } u;
    u.s = (short8_t){0, 0, 0, 0, 0, 0, 0, 0};
    return u.b;
}

// ---------------------------------------------------------------- concat
__global__ void k_concat(const float* __restrict__ x, const float* __restrict__ cls,
                         float* __restrict__ h) {
    int idx = blockIdx.x * 256 + threadIdx.x;
    if (idx >= NTOK * DIM) return;
    int row = idx / DIM, col = idx % DIM;
    h[idx] = (row == 0) ? cls[col] : x[(row - 1) * DIM + col];
}

// ---------------------------------------------------------------- layernorm -> bf16 padded A
__global__ void k_layernorm_bf(const float* __restrict__ h, const float* __restrict__ w,
                               const float* __restrict__ b, __hip_bfloat16* __restrict__ xbf) {
    int row = blockIdx.x;
    const float* r = h + (long)row * DIM;
    int t = threadIdx.x;
    float v0 = r[t], v1 = r[t + 256];
    __shared__ float red[256];
    red[t] = v0 + v1; __syncthreads();
    for (int o = 128; o > 0; o >>= 1) { if (t < o) red[t] += red[t + o]; __syncthreads(); }
    float mu = red[0] * (1.f / DIM); __syncthreads();
    float d0 = v0 - mu, d1 = v1 - mu;
    red[t] = d0 * d0 + d1 * d1; __syncthreads();
    for (int o = 128; o > 0; o >>= 1) { if (t < o) red[t] += red[t + o]; __syncthreads(); }
    float rstd = rsqrtf(red[0] * (1.f / DIM) + 1e-5f);
    long base = (long)(PADR + row) * DIM;
    xbf[base + t]       = __float2bfloat16(d0 * rstd * w[t] + b[t]);
    xbf[base + t + 256] = __float2bfloat16(d1 * rstd * w[t + 256] + b[t + 256]);
}

// ---------------------------------------------------------------- helpers
__global__ void k_zero(float* __restrict__ p, int n) {
    int i = blockIdx.x * 256 + threadIdx.x;
    if (i < n) p[i] = 0.f;
}
__global__ void k_zerobf(__hip_bfloat16* __restrict__ p, int n) {
    int i = blockIdx.x * 256 + threadIdx.x;
    if (i < n) p[i] = __float2bfloat16(0.f);
}
__global__ void k_cvt(const float* __restrict__ s, __hip_bfloat16* __restrict__ d, int n) {
    int i = blockIdx.x * 256 + threadIdx.x;
    if (i < n) d[i] = __float2bfloat16(s[i]);
}
__global__ void k_cvt_pad(const float* __restrict__ s, __hip_bfloat16* __restrict__ d,
                          int rows_src, int rows_dst, int cols) {
    int i = blockIdx.x * 256 + threadIdx.x;
    if (i >= rows_dst * cols) return;
    int row = i / cols;
    d[i] = __float2bfloat16(row < rows_src ? s[i] : 0.f);
}
__global__ void k_wt_cvt(const float* __restrict__ W, __hip_bfloat16* __restrict__ Wt,
                         int K, int N) {
    __shared__ float tile[32][33];
    int k0 = blockIdx.x * 32, n0 = blockIdx.y * 32;
    int lx = threadIdx.x % 32, ly = threadIdx.x / 32;
    for (int i = 0; i < 32; i += 8) tile[ly + i][lx] = W[(long)(k0 + ly + i) * N + n0 + lx];
    __syncthreads();
    for (int i = 0; i < 32; i += 8)
        Wt[(long)(n0 + ly + i) * K + k0 + lx] = __float2bfloat16(tile[lx][ly + i]);
}
// v slice of qkvbf -> vt bf16 [c][n]
__global__ void k_vt(const __hip_bfloat16* __restrict__ qkvbf, __hip_bfloat16* __restrict__ vt) {
    __shared__ __hip_bfloat16 tile[32][33];
    int n0 = blockIdx.x * 32, c0 = blockIdx.y * 32;
    int lx = threadIdx.x % 32, ly = threadIdx.x / 32;
    for (int i = 0; i < 32; i += 8)
        tile[ly + i][lx] = qkvbf[(long)(n0 + ly + i) * QKVLD + 1024 + c0 + lx];
    __syncthreads();
    for (int i = 0; i < 32; i += 8)
        vt[(long)(c0 + ly + i) * NPAD + n0 + lx] = tile[lx][ly + i];
}
// a3v fp32 [h][256][64] -> a3vt bf16 [h][64][256]
__global__ void k_a3vt(const float* __restrict__ a3v, __hip_bfloat16* __restrict__ a3vt) {
    __shared__ float tile[32][33];
    int h = blockIdx.z;
    int d0 = blockIdx.x * 32, m0 = blockIdx.y * 32;
    long base = (long)h * 16384;
    int lx = threadIdx.x % 32, ly = threadIdx.x / 32;
    for (int i = 0; i < 32; i += 8)
        tile[ly + i][lx] = a3v[base + (long)(m0 + ly + i) * 64 + d0 + lx];
    __syncthreads();
    for (int i = 0; i < 32; i += 8)
        a3vt[base + (long)(d0 + ly + i) * 256 + m0 + lx] = __float2bfloat16(tile[lx][ly + i]);
}

// ---------------------------------------------------------------- MFMA GEMM 128x128 (LDS-staged), optional fp32/bf16 out
__global__ __launch_bounds__(256) void k_mfma_gemm(
    const __hip_bfloat16* __restrict__ A, const __hip_bfloat16* __restrict__ Bt,
    float* __restrict__ C, int M, int N, int K, int Mstore,
    int scale_cols, float scale_val, const float* __restrict__ bias, int accum,
    __hip_bfloat16* __restrict__ Cbf)
{
    __shared__ unsigned short As[128 * 40];
    __shared__ unsigned short Bs[128 * 40];
    int tid = threadIdx.x;
    int m0 = blockIdx.y * 128, n0 = blockIdx.x * 128;
    int wave = tid >> 6, lane = tid & 63;
    int wm = (wave & 1) * 64, wn = (wave >> 1) * 64;
    f32x4_t zero4 = {0.f, 0.f, 0.f, 0.f};
    f32x4_t acc[4][4];
#pragma unroll
    for (int i = 0; i < 4; i++)
#pragma unroll
        for (int j = 0; j < 4; j++) acc[i][j] = zero4;
    int srow = tid >> 2, skc = (tid & 3) * 8;
    int quad = lane >> 4, fr = lane & 15;

    for (int k0 = 0; k0 < K; k0 += 32) {
        uint4 av0 = *(const uint4*)(A + (long)(m0 + srow) * K + k0 + skc);
        uint4 av1 = *(const uint4*)(A + (long)(m0 + srow + 64) * K + k0 + skc);
        uint4 bv0 = *(const uint4*)(Bt + (long)(n0 + srow) * K + k0 + skc);
        uint4 bv1 = *(const uint4*)(Bt + (long)(n0 + srow + 64) * K + k0 + skc);
        __syncthreads();
        *(uint4*)&As[srow * 40 + skc] = av0;
        *(uint4*)&As[(srow + 64) * 40 + skc] = av1;
        *(uint4*)&Bs[srow * 40 + skc] = bv0;
        *(uint4*)&Bs[(srow + 64) * 40 + skc] = bv1;
        __syncthreads();
        bf16x8_t af[4], bq[4];
#pragma unroll
        for (int i = 0; i < 4; i++) {
            af[i] = *(const bf16x8_t*)&As[(wm + i * 16 + fr) * 40 + quad * 8];
            bq[i] = *(const bf16x8_t*)&Bs[(wn + i * 16 + fr) * 40 + quad * 8];
        }
#pragma unroll
        for (int i = 0; i < 4; i++)
#pragma unroll
            for (int j = 0; j < 4; j++)
                acc[i][j] = __builtin_amdgcn_mfma_f32_16x16x32_bf16(af[i], bq[j], acc[i][j], 0, 0, 0);
    }
    int col = lane & 15, rq = lane >> 4;
#pragma unroll
    for (int j = 0; j < 4; j++) {
        int c = n0 + wn + j * 16 + col;
        float bsv = bias ? bias[c] : 0.f;
        float sc = (c < scale_cols) ? scale_val : 1.f;
#pragma unroll
        for (int i = 0; i < 4; i++) {
            int rbase = m0 + wm + i * 16 + rq * 4;
#pragma unroll
            for (int rr = 0; rr < 4; rr++) {
                int r = rbase + rr;
                if (r >= Mstore) continue;
                float v = acc[i][j][rr] * sc + bsv;
                long off = (long)r * N + c;
                if (C) { if (accum) C[off] += v; else C[off] = v; }
                if (Cbf) Cbf[off] = __float2bfloat16(v);
            }
        }
    }
}

// ---------------------------------------------------------------- generic MFMA NT scores kernel, 128x128, no LDS
__global__ __launch_bounds__(256) void k_mfma_nt(
    const __hip_bfloat16* __restrict__ A, long lda, long abatch, int arowmax,
    const __hip_bfloat16* __restrict__ Bt, long ldb, long bbatch,
    float* __restrict__ C, long ldc, long cbatch, int crowmax, int K)
{
    int h = blockIdx.z;
    const __hip_bfloat16* Ab = A + (long)h * abatch;
    const __hip_bfloat16* Bb = Bt + (long)h * bbatch;
    float* Cb = C + (long)h * cbatch;
    int m0 = blockIdx.y * 128, n0 = blockIdx.x * 128;
    int wave = threadIdx.x >> 6, lane = threadIdx.x & 63;
    int wm = (wave & 1) * 64, wn = (wave >> 1) * 64;
    int fr = lane & 15, quad = lane >> 4;
    f32x4_t zero4 = {0.f, 0.f, 0.f, 0.f};
    f32x4_t acc[4][4];
#pragma unroll
    for (int i = 0; i < 4; i++)
#pragma unroll
        for (int j = 0; j < 4; j++) acc[i][j] = zero4;
    for (int k0 = 0; k0 < K; k0 += 32) {
        bf16x8_t af[4], bq[4];
#pragma unroll
        for (int i = 0; i < 4; i++) {
            int r = m0 + wm + i * 16 + fr;
            af[i] = (r < arowmax) ? *(const bf16x8_t*)(Ab + (long)r * lda + k0 + quad * 8)
                                  : bzero8();
        }
#pragma unroll
        for (int j = 0; j < 4; j++) {
            int n = n0 + wn + j * 16 + fr;
            bq[j] = *(const bf16x8_t*)(Bb + (long)n * ldb + k0 + quad * 8);
        }
#pragma unroll
        for (int i = 0; i < 4; i++)
#pragma unroll
            for (int j = 0; j < 4; j++)
                acc[i][j] = __builtin_amdgcn_mfma_f32_16x16x32_bf16(af[i], bq[j], acc[i][j], 0, 0, 0);
    }
#pragma unroll
    for (int i = 0; i < 4; i++)
#pragma unroll
        for (int j = 0; j < 4; j++)
#pragma unroll
            for (int rr = 0; rr < 4; rr++) {
                int r = m0 + wm + i * 16 + quad * 4 + rr;
                int c = n0 + wn + j * 16 + fr;
                if (r < crowmax) Cb[(long)r * ldc + c] = acc[i][j][rr];
            }
}

// ---------------------------------------------------------------- generic MFMA 128x64 tile, split-K / accum / bf16-T out
// mode 0: atomicAdd fp32; mode 1: fp32 +=; mode 2: bf16 transposed store
__global__ __launch_bounds__(256) void k_mfma_t64(
    const __hip_bfloat16* __restrict__ A, long lda, long abatch, int arowmax,
    const __hip_bfloat16* __restrict__ Bt, long ldb, long bbatch,
    float* __restrict__ Cf, __hip_bfloat16* __restrict__ Cbf,
    long ldc, long cbatch, int crowmax, int ksplit, int mode)
{
    int h = blockIdx.z;
    const __hip_bfloat16* Ab = A + (long)h * abatch;
    const __hip_bfloat16* Bb = Bt + (long)h * bbatch;
    int m0 = blockIdx.y * 128;
    int kbeg = blockIdx.x * ksplit, kend = kbeg + ksplit;
    int wave = threadIdx.x >> 6, lane = threadIdx.x & 63;
    int wm = (wave & 1) * 64, wn = (wave >> 1) * 32;
    int fr = lane & 15, quad = lane >> 4;
    f32x4_t zero4 = {0.f, 0.f, 0.f, 0.f};
    f32x4_t acc[4][2];
#pragma unroll
    for (int i = 0; i < 4; i++) { acc[i][0] = zero4; acc[i][1] = zero4; }
    for (int k0 = kbeg; k0 < kend; k0 += 32) {
        bf16x8_t bq[2];
#pragma unroll
        for (int j = 0; j < 2; j++)
            bq[j] = *(const bf16x8_t*)(Bb + (long)(wn + j * 16 + fr) * ldb + k0 + quad * 8);
#pragma unroll
        for (int i = 0; i < 4; i++) {
            int r = m0 + wm + i * 16 + fr;
            bf16x8_t af = (r < arowmax) ? *(const bf16x8_t*)(Ab + (long)r * lda + k0 + quad * 8)
                                        : bzero8();
#pragma unroll
            for (int j = 0; j < 2; j++)
                acc[i][j] = __builtin_amdgcn_mfma_f32_16x16x32_bf16(af, bq[j], acc[i][j], 0, 0, 0);
        }
    }
#pragma unroll
    for (int i = 0; i < 4; i++)
#pragma unroll
        for (int j = 0; j < 2; j++)
#pragma unroll
            for (int rr = 0; rr < 4; rr++) {
                int r = m0 + wm + i * 16 + quad * 4 + rr;
                int c = wn + j * 16 + fr;
                float v = acc[i][j][rr];
                if (mode == 0) {
                    atomicAdd(Cf + (long)h * cbatch + (long)r * ldc + c, v);
                } else if (mode == 1) {
                    if (r < crowmax) Cf[(long)h * cbatch + (long)r * ldc + c] += v;
                } else {
                    Cbf[(long)h * cbatch + (long)c * ldc + r] = __float2bfloat16(v);
                }
            }
}

// ---------------------------------------------------------------- pinv phase: C = s*(A@B) + acoef*Aadd, per head
// 128x128 tile, K=256, no LDS (L2-resident operands); writes bf16 row and/or transposed.
__global__ __launch_bounds__(256) void k_mm256(
    const __hip_bfloat16* __restrict__ Aa, const __hip_bfloat16* __restrict__ Bt,
    float s, float acoef, const __hip_bfloat16* __restrict__ Aadd,
    __hip_bfloat16* __restrict__ Ca, __hip_bfloat16* __restrict__ Ct)
{
    int hd = blockIdx.z;
    long hb = (long)hd * 65536;
    int m0 = blockIdx.y * 128, n0 = blockIdx.x * 128;
    int wave = threadIdx.x >> 6, lane = threadIdx.x & 63;
    int wm = (wave & 1) * 64, wn = (wave >> 1) * 64;
    int fr = lane & 15, quad = lane >> 4;
    f32x4_t zero4 = {0.f, 0.f, 0.f, 0.f};
    f32x4_t acc[4][4];
#pragma unroll
    for (int i = 0; i < 4; i++)
#pragma unroll
        for (int j = 0; j < 4; j++) acc[i][j] = zero4;
#pragma unroll
    for (int k0 = 0; k0 < 256; k0 += 32) {
        bf16x8_t af[4], bq[4];
#pragma unroll
        for (int i = 0; i < 4; i++)
            af[i] = *(const bf16x8_t*)(Aa + hb + (long)(m0 + wm + i * 16 + fr) * 256 + k0 + quad * 8);
#pragma unroll
        for (int j = 0; j < 4; j++)
            bq[j] = *(const bf16x8_t*)(Bt + hb + (long)(n0 + wn + j * 16 + fr) * 256 + k0 + quad * 8);
#pragma unroll
        for (int i = 0; i < 4; i++)
#pragma unroll
            for (int j = 0; j < 4; j++)
                acc[i][j] = __builtin_amdgcn_mfma_f32_16x16x32_bf16(af[i], bq[j], acc[i][j], 0, 0, 0);
    }
#pragma unroll
    for (int i = 0; i < 4; i++)
#pragma unroll
        for (int j = 0; j < 4; j++)
#pragma unroll
            for (int rr = 0; rr < 4; rr++) {
                int r = m0 + wm + i * 16 + quad * 4 + rr;
                int c = n0 + wn + j * 16 + fr;
                float v = s * acc[i][j][rr];
                if (Aadd) v += acoef * __bfloat162float(Aadd[hb + (long)r * 256 + c]);
                __hip_bfloat16 bv = __float2bfloat16(v);
                if (Ca) Ca[hb + (long)r * 256 + c] = bv;
                if (Ct) Ct[hb + (long)c * 256 + r] = bv;
            }
}

// ---------------------------------------------------------------- landmark means (bf16 in; fp32 + bf16 out)
__global__ void k_landmarks(const __hip_bfloat16* __restrict__ qkvbf, float* __restrict__ ql,
                            float* __restrict__ kl, __hip_bfloat16* __restrict__ qlbf,
                            __hip_bfloat16* __restrict__ klbf) {
    int m = blockIdx.x, h = blockIdx.y, d = threadIdx.x;
    float sq = 0.f, sk = 0.f;
    for (int j = 0; j < LFAC; j++) {
        long base = (long)(m * LFAC + j) * QKVLD + h * DHD + d;
        sq += __bfloat162float(qkvbf[base]);
        sk += __bfloat162float(qkvbf[base + 512]);
    }
    long o = ((long)h * MLAND + m) * DHD + d;
    float vq = sq * (1.f / LFAC), vk = sk * (1.f / LFAC);
    ql[o] = vq; kl[o] = vk;
    qlbf[o] = __float2bfloat16(vq);
    klbf[o] = __float2bfloat16(vk);
}

// ---------------------------------------------------------------- attn2 = softmax(q_l @ k_l^T) fp32
__global__ void k_attn2(const float* __restrict__ ql, const float* __restrict__ kl,
                        float* __restrict__ attn2) {
    int i = blockIdx.x, h = blockIdx.y, j = threadIdx.x;
    __shared__ float q[64];
    __shared__ float red[256];
    if (j < 64) q[j] = ql[((long)h * MLAND + i) * DHD + j];
    __syncthreads();
    const float* kr = kl + ((long)h * MLAND + j) * DHD;
    float s = 0.f;
#pragma unroll 8
    for (int d = 0; d < 64; d++) s += q[d] * kr[d];
    red[j] = s; __syncthreads();
    for (int o = 128; o > 0; o >>= 1) { if (j < o) red[j] = fmaxf(red[j], red[j + o]); __syncthreads(); }
    float mx = red[0]; __syncthreads();
    float e = __expf(s - mx);
    red[j] = e; __syncthreads();
    for (int o = 128; o > 0; o >>= 1) { if (j < o) red[j] += red[j + o]; __syncthreads(); }
    attn2[((long)h * MLAND + i) * MLAND + j] = e / red[0];
}

// ---------------------------------------------------------------- pinv scale: max |row/col sums|
__global__ void k_colrow(const float* __restrict__ x, float* __restrict__ scal) {
    int h = blockIdx.x, t = threadIdx.x;
    const float* xh = x + (long)h * MLAND * MLAND;
    float cs = 0.f, rs = 0.f;
    for (int j = 0; j < MLAND; j++) {
        cs += fabsf(xh[(long)t * MLAND + j]);
        rs += fabsf(xh[(long)j * MLAND + t]);
    }
    __shared__ float red[256];
    red[t] = cs; __syncthreads();
    for (int o = 128; o > 0; o >>= 1) { if (t < o) red[t] = fmaxf(red[t], red[t + o]); __syncthreads(); }
    if (t == 0) atomicMax((int*)&scal[0], __float_as_int(red[0]));
    __syncthreads();
    red[t] = rs; __syncthreads();
    for (int o = 128; o > 0; o >>= 1) { if (t < o) red[t] = fmaxf(red[t], red[t + o]); __syncthreads(); }
    if (t == 0) atomicMax((int*)&scal[1], __float_as_int(red[0]));
}

// ---------------------------------------------------------------- z0 init (za = x^T*inv, zt = x*inv)
__global__ void k_tscale2(const float* __restrict__ x, const float* __restrict__ scal,
                          __hip_bfloat16* __restrict__ za, __hip_bfloat16* __restrict__ zt) {
    int h = blockIdx.z;
    int tj = blockIdx.x * 32, ti = blockIdx.y * 32;
    __shared__ float tile[32][33];
    const float* xh = x + (long)h * 65536;
    int lx = threadIdx.x % 32, ly = threadIdx.x / 32;
    float inv = 1.f / (scal[0] * scal[1]);
    for (int yy = 0; yy < 32; yy += 8) {
        float v = xh[(long)(ti + ly + yy) * MLAND + tj + lx];
        tile[ly + yy][lx] = v;
        zt[(long)h * 65536 + (long)(ti + ly + yy) * MLAND + tj + lx] = __float2bfloat16(v * inv);
    }
    __syncthreads();
    for (int yy = 0; yy < 32; yy += 8)
        za[(long)h * 65536 + (long)(tj + ly + yy) * MLAND + ti + lx] =
            __float2bfloat16(tile[lx][ly + yy] * inv);
}

// ---------------------------------------------------------------- softmax over 10240, in-place bf16 out (first half of row)
__global__ __launch_bounds__(256) void k_softmax3(float* S) {
    long row = blockIdx.x;
    float* r = S + row * NPAD;
    __hip_bfloat16* ob = (__hip_bfloat16*)S + row * (2L * NPAD);
    int t = threadIdx.x;
    float v[40];
    float mx = -1e30f;
#pragma unroll
    for (int j = 0; j < 40; j++) { v[j] = r[t + j * 256]; mx = fmaxf(mx, v[j]); }
    __shared__ float red[256];
    red[t] = mx; __syncthreads();
    for (int o = 128; o > 0; o >>= 1) { if (t < o) red[t] = fmaxf(red[t], red[t + o]); __syncthreads(); }
    mx = red[0]; __syncthreads();
    float s = 0.f;
#pragma unroll
    for (int j = 0; j < 40; j++) { v[j] = __expf(v[j] - mx); s += v[j]; }
    red[t] = s; __syncthreads();
    for (int o = 128; o > 0; o >>= 1) { if (t < o) red[t] += red[t + o]; __syncthreads(); }
    float inv = 1.f / red[0];
#pragma unroll
    for (int j = 0; j < 40; j++) ob[t + j * 256] = __float2bfloat16(v[j] * inv);
}

// ---------------------------------------------------------------- softmax over 256 (attn1), in-place bf16 out
__global__ void k_softmax1(float* S) {
    int h = blockIdx.y;
    int i = blockIdx.x * 4 + (threadIdx.x >> 6);
    if (i >= NTOK) return;
    int lane = threadIdx.x & 63;
    const float* r = S + ((long)h * PSTR + i) * MLAND + lane * 4;
    float4 v = *(const float4*)r;
    float mx = fmaxf(fmaxf(v.x, v.y), fmaxf(v.z, v.w));
#pragma unroll
    for (int o = 32; o > 0; o >>= 1) mx = fmaxf(mx, __shfl_xor(mx, o));
    float e0 = __expf(v.x - mx), e1 = __expf(v.y - mx);
    float e2 = __expf(v.z - mx), e3 = __expf(v.w - mx);
    float s = e0 + e1 + e2 + e3;
#pragma unroll
    for (int o = 32; o > 0; o >>= 1) s += __shfl_xor(s, o);
    float inv = 1.f / s;
    __hip_bfloat16* ob = (__hip_bfloat16*)S + ((long)h * PSTR + i) * 512L + lane * 4;
    ob[0] = __float2bfloat16(e0 * inv);
    ob[1] = __float2bfloat16(e1 * inv);
    ob[2] = __float2bfloat16(e2 * inv);
    ob[3] = __float2bfloat16(e3 * inv);
}

// ---------------------------------------------------------------- conv residual -> aout (bf16 v)
__global__ void k_conv_res(const __hip_bfloat16* __restrict__ qkvbf, const float* __restrict__ resw,
                           float* __restrict__ aout) {
    int e = blockIdx.x * 256 + threadIdx.x;
    if (e >= NTOK * DIM) return;
    int i = e >> 9, c = e & 511;
    int hh = c >> 6;
    int n = PADR + i;
    float acc = 0.f;
#pragma unroll
    for (int t = 0; t < 33; t++) {
        int nn = n - 16 + t;
        if (nn < NPAD)
            acc += resw[hh * 33 + t] * __bfloat162float(qkvbf[(long)nn * QKVLD + 1024 + c]);
    }
    aout[e] = acc;
}

// ---------------------------------------------------------------- ppeg transposes + combined 49-tap conv
__global__ void k_tfwd(const float* __restrict__ h, float* __restrict__ ft) {
    __shared__ float tile[32][33];
    int t0 = blockIdx.x * 32, c0 = blockIdx.y * 32;
    int lx = threadIdx.x % 32, ly = threadIdx.x / 32;
    for (int i = 0; i < 32; i += 8) {
        int t = t0 + ly + i;
        if (t < NPATCH) tile[ly + i][lx] = h[(long)(1 + t) * DIM + c0 + lx];
    }
    __syncthreads();
    for (int i = 0; i < 32; i += 8) {
        int c = c0 + ly + i, t = t0 + lx;
        if (t < NPATCH) ft[(long)c * NPATCH + t] = tile[lx][ly + i];
    }
}

__global__ __launch_bounds__(256) void k_ppeg2(
    const float* __restrict__ ft, float* __restrict__ yt,
    const float* __restrict__ w7, const float* __restrict__ b7,
    const float* __restrict__ w5, const float* __restrict__ b5,
    const float* __restrict__ w3, const float* __restrict__ b3)
{
    int s = blockIdx.x, c = blockIdx.y;
    __shared__ float tile[26][106];
    __shared__ float wt[49];
    int tid = threadIdx.x;
    int r0 = s * 20 - 3;
    for (int idx = tid; idx < 26 * 106; idx += 256) {
        int rr = idx / 106, cc = idx % 106;
        int gy = r0 + rr, gx = cc - 3;
        float v = 0.f;
        if (gy >= 0 && gy < 100 && gx >= 0 && gx < 100)
            v = ft[(long)c * NPATCH + gy * 100 + gx];
        tile[rr][cc] = v;
    }
    if (tid < 49) {
        int dy = tid / 7 - 3, dx = tid % 7 - 3;
        float w = w7[c * 49 + tid];
        if (dy >= -2 && dy <= 2 && dx >= -2 && dx <= 2) w += w5[c * 25 + (dy + 2) * 5 + (dx + 2)];
        if (dy >= -1 && dy <= 1 && dx >= -1 && dx <= 1) w += w3[c * 9 + (dy + 1) * 3 + (dx + 1)];
        wt[tid] = w;
    }
    __syncthreads();
    float bsum = b7[c] + b5[c] + b3[c];
    for (int p = tid; p < 2000; p += 256) {
        int ly = p / 100, lx = p % 100;
        float acc = tile[ly + 3][lx + 3] + bsum;
#pragma unroll
        for (int dy = 0; dy < 7; dy++)
#pragma unroll
            for (int dx = 0; dx < 7; dx++)
                acc += wt[dy * 7 + dx] * tile[ly + dy][lx + dx];
        yt[(long)c * NPATCH + (s * 20 + ly) * 100 + lx] = acc;
    }
}

__global__ void k_tback(const float* __restrict__ yt, float* __restrict__ h) {
    __shared__ float tile[32][33];
    int t0 = blockIdx.x * 32, c0 = blockIdx.y * 32;
    int lx = threadIdx.x % 32, ly = threadIdx.x / 32;
    for (int i = 0; i < 32; i += 8) {
        int c = c0 + ly + i, t = t0 + lx;
        if (t < NPATCH) tile[ly + i][lx] = yt[(long)c * NPATCH + t];
    }
    __syncthreads();
    for (int i = 0; i < 32; i += 8) {
        int t = t0 + ly + i;
        if (t < NPATCH) h[(long)(1 + t) * DIM + c0 + lx] = tile[lx][ly + i];
    }
}

// ---------------------------------------------------------------- final LN + heads + softmax
__global__ void k_final(const float* __restrict__ h, const float* __restrict__ nw,
                        const float* __restrict__ nb,
                        const float* __restrict__ fc2w, const float* __restrict__ fc2b,
                        const float* __restrict__ pcw, const float* __restrict__ pcb,
                        float* __restrict__ out)
{
    int row = blockIdx.x;
    int t = threadIdx.x;
    const float* r = h + (long)row * DIM;
    float v0 = r[t], v1 = r[t + 256];
    __shared__ float red[256];
    red[t] = v0 + v1; __syncthreads();
    for (int o = 128; o > 0; o >>= 1) { if (t < o) red[t] += red[t + o]; __syncthreads(); }
    float mu = red[0] * (1.f / DIM); __syncthreads();
    float d0 = v0 - mu, d1 = v1 - mu;
    red[t] = d0 * d0 + d1 * d1; __syncthreads();
    for (int o = 128; o > 0; o >>= 1) { if (t < o) red[t] += red[t + o]; __syncthreads(); }
    float rstd = rsqrtf(red[0] * (1.f / DIM) + 1e-5f); __syncthreads();
    float h0 = d0 * rstd * nw[t] + nb[t];
    float h1 = d1 * rstd * nw[t + 256] + nb[t + 256];
    const float* w = (row == 0) ? fc2w : pcw;
    float p0 = h0 * w[t * 2] + h1 * w[(t + 256) * 2];
    float p1 = h0 * w[t * 2 + 1] + h1 * w[(t + 256) * 2 + 1];
    red[t] = p0; __syncthreads();
    for (int o = 128; o > 0; o >>= 1) { if (t < o) red[t] += red[t + o]; __syncthreads(); }
    float l0 = red[0]; __syncthreads();
    red[t] = p1; __syncthreads();
    for (int o = 128; o > 0; o >>= 1) { if (t < o) red[t] += red[t + o]; __syncthreads(); }
    if (t == 0) {
        float l1 = red[0];
        const float* bb = (row == 0) ? fc2b : pcb;
        float a0 = l0 + bb[0], a1 = l1 + bb[1];
        if (row == 0) { out[0] = a0; out[1] = a1; }
        else {
            long i = row - 1;
            out[2 + i * 2] = a0;
            out[2 + i * 2 + 1] = a1;
            float m = fmaxf(a0, a1);
            float e0 = __expf(a0 - m), e1 = __expf(a1 - m);
            float inv = 1.f / (e0 + e1);
            out[2 + 2 * NPATCH + i * 2] = e0 * inv;
            out[2 + 2 * NPATCH + i * 2 + 1] = e1 * inv;
        }
    }
}

// ================================================================ launcher
extern "C" void kernel_launch(void* const* d_in, const int* in_sizes, int n_in,
                              void* d_out, int out_size, void* d_ws, size_t ws_size,
                              hipStream_t stream)
{
    const float* x     = (const float*)d_in[0];
    const float* cls   = (const float*)d_in[1];
    const float* ln1w  = (const float*)d_in[2];
    const float* ln1b  = (const float*)d_in[3];
    const float* qkv1w = (const float*)d_in[4];
    const float* out1w = (const float*)d_in[5];
    const float* out1b = (const float*)d_in[6];
    const float* res1w = (const float*)d_in[7];
    const float* p7w   = (const float*)d_in[8];
    const float* p7b   = (const float*)d_in[9];
    const float* p5w   = (const float*)d_in[10];
    const float* p5b   = (const float*)d_in[11];
    const float* p3w   = (const float*)d_in[12];
    const float* p3b   = (const float*)d_in[13];
    const float* ln2w  = (const float*)d_in[14];
    const float* ln2b  = (const float*)d_in[15];
    const float* qkv2w = (const float*)d_in[16];
    const float* out2w = (const float*)d_in[17];
    const float* out2b = (const float*)d_in[18];
    const float* res2w = (const float*)d_in[19];
    const float* normw = (const float*)d_in[20];
    const float* normb = (const float*)d_in[21];
    const float* fc2w  = (const float*)d_in[22];
    const float* fc2b  = (const float*)d_in[23];
    const float* pcw   = (const float*)d_in[24];
    const float* pcb   = (const float*)d_in[25];
    float* out = (float*)d_out;

    float* p = (float*)d_ws;
    float* h      = p; p += 5120512;     // 10001 x 512
    float* aout   = p; p += 5120512;     // 10001 x 512 (also ppeg yt)
    float* ql     = p; p += 131072;
    float* kl     = p; p += 131072;
    float* x2     = p; p += 524288;
    float* a3v    = p; p += 131072;
    float* scal   = p; p += 8;
    float* attn3f = p; p += 20971520;    // fp32 scores; softmax converts in-place to bf16; also aliases ft
    __hip_bfloat16* qkvbf = (__hip_bfloat16*)p; p += 7864320;   // 10240 x 1536
    __hip_bfloat16* xbf   = (__hip_bfloat16*)p; p += 2621440;   // 10240 x 512
    __hip_bfloat16* abf   = (__hip_bfloat16*)p; p += 2588672;   // 10112 x 512
    __hip_bfloat16* qw1t  = (__hip_bfloat16*)p; p += 393216;
    __hip_bfloat16* qw2t  = (__hip_bfloat16*)p; p += 393216;
    __hip_bfloat16* ow1t  = (__hip_bfloat16*)p; p += 131072;
    __hip_bfloat16* ow2t  = (__hip_bfloat16*)p; p += 131072;
    __hip_bfloat16* x2a   = (__hip_bfloat16*)p; p += 262144;
    __hip_bfloat16* za    = (__hip_bfloat16*)p; p += 262144;
    __hip_bfloat16* zt    = (__hip_bfloat16*)p; p += 262144;
    __hip_bfloat16* za2   = (__hip_bfloat16*)p; p += 262144;
    __hip_bfloat16* zt2   = (__hip_bfloat16*)p; p += 262144;
    __hip_bfloat16* xza   = (__hip_bfloat16*)p; p += 262144;
    __hip_bfloat16* xzt   = (__hip_bfloat16*)p; p += 262144;
    __hip_bfloat16* t1t   = (__hip_bfloat16*)p; p += 262144;
    __hip_bfloat16* t2t   = (__hip_bfloat16*)p; p += 262144;
    __hip_bfloat16* qlbf  = (__hip_bfloat16*)p; p += 65536;
    __hip_bfloat16* klbf  = (__hip_bfloat16*)p; p += 65536;
    __hip_bfloat16* vt    = (__hip_bfloat16*)p; p += 2621440;   // 8 x 64 x 10240
    __hip_bfloat16* a3vt  = (__hip_bfloat16*)p; p += 65536;
    __hip_bfloat16* w2bt  = (__hip_bfloat16*)p; p += 65536;
    float* ft = attn3f;   // ppeg channel-major buffer aliases dead score buffer
    float* yt = aout;

    k_concat<<<dim3((NTOK * DIM + 255) / 256), 256, 0, stream>>>(x, cls, h);
    k_wt_cvt<<<dim3(16, 48), 256, 0, stream>>>(qkv1w, qw1t, 512, 1536);
    k_wt_cvt<<<dim3(16, 48), 256, 0, stream>>>(qkv2w, qw2t, 512, 1536);
    k_wt_cvt<<<dim3(16, 16), 256, 0, stream>>>(out1w, ow1t, 512, 512);
    k_wt_cvt<<<dim3(16, 16), 256, 0, stream>>>(out2w, ow2t, 512, 512);
    k_zerobf<<<dim3((PADR * DIM + 255) / 256), 256, 0, stream>>>(xbf, PADR * DIM);

    auto layer = [&](const float* lnw, const float* lnb, const __hip_bfloat16* qwt,
                     const __hip_bfloat16* owt, const float* outb, const float* resw) {
        k_layernorm_bf<<<NTOK, 256, 0, stream>>>(h, lnw, lnb, xbf);
        k_mfma_gemm<<<dim3(12, 80), 256, 0, stream>>>(xbf, qwt, nullptr, NPAD, QKVLD, 512,
                                                      NPAD, 512, 0.125f, nullptr, 0, qkvbf);
        k_vt<<<dim3(320, 16), 256, 0, stream>>>(qkvbf, vt);
        k_landmarks<<<dim3(MLAND, HEADS), 64, 0, stream>>>(qkvbf, ql, kl, qlbf, klbf);
        k_attn2<<<dim3(MLAND, HEADS), 256, 0, stream>>>(ql, kl, x2);
        k_zero<<<1, 64, 0, stream>>>(scal, 8);
        k_colrow<<<HEADS, 256, 0, stream>>>(x2, scal);
        k_cvt<<<dim3(2048), 256, 0, stream>>>(x2, x2a, HEADS * 65536);
        k_tscale2<<<dim3(8, 8, HEADS), 256, 0, stream>>>(x2, scal, za, zt);
        // pinv: 24 launch-bound MFMA phases (all heads parallel, 32 blocks each)
        {
            __hip_bfloat16 *zra = za, *zrt = zt, *zoa = za2, *zot = zt2;
            dim3 g(2, 2, HEADS);
            for (int it = 0; it < 6; it++) {
                k_mm256<<<g, 256, 0, stream>>>(x2a, zrt, 1.f, 0.f, nullptr, xza, xzt);
                k_mm256<<<g, 256, 0, stream>>>(xza, xzt, -1.f, 7.f, xza, nullptr, t1t);
                k_mm256<<<g, 256, 0, stream>>>(xza, t1t, -1.f, 15.f, xza, nullptr, t2t);
                k_mm256<<<g, 256, 0, stream>>>(zra, t2t, -0.25f, 3.25f, zra, zoa, zot);
                __hip_bfloat16* tmp;
                tmp = zra; zra = zoa; zoa = tmp;
                tmp = zrt; zrt = zot; zot = tmp;
            }
            // final z row-major bf16 ends in za (6 swaps)
        }
        // attn3: scores (MFMA) -> softmax (in-place bf16) -> @v (MFMA split-K)
        k_mfma_nt<<<dim3(80, 2, HEADS), 256, 0, stream>>>(
            qlbf, 64, 16384, 256, qkvbf + 512, QKVLD, 64,
            attn3f, NPAD, (long)256 * NPAD, 256, 64);
        k_softmax3<<<2048, 256, 0, stream>>>(attn3f);
        k_zero<<<512, 256, 0, stream>>>(a3v, 131072);
        k_mfma_t64<<<dim3(16, 2, HEADS), 256, 0, stream>>>(
            (__hip_bfloat16*)attn3f, 2L * NPAD, (long)256 * 2 * NPAD, 256,
            vt, NPAD, (long)64 * NPAD,
            a3v, nullptr, 64, 16384, 256, 640, 0);
        k_a3vt<<<dim3(2, 8, HEADS), 256, 0, stream>>>(a3v, a3vt);
        // w2b^T = (z @ a3v)^T bf16
        k_mfma_t64<<<dim3(1, 2, HEADS), 256, 0, stream>>>(
            za, 256, 65536, 256, a3vt, 256, 16384,
            nullptr, w2bt, 256, 16384, 256, 256, 2);
        // attn1: scores (MFMA) -> softmax (in-place bf16) -> conv residual -> +P@w2 (MFMA)
        k_mfma_nt<<<dim3(2, 79, HEADS), 256, 0, stream>>>(
            qkvbf + (long)PADR * QKVLD, QKVLD, 64, NTOK, klbf, 64, 16384,
            attn3f, 256, (long)PSTR * 256, NTOK, 64);
        k_softmax1<<<dim3(2501, HEADS), 256, 0, stream>>>(attn3f);
        k_conv_res<<<dim3((NTOK * DIM + 255) / 256), 256, 0, stream>>>(qkvbf, resw, aout);
        k_mfma_t64<<<dim3(1, 79, HEADS), 256, 0, stream>>>(
            (__hip_bfloat16*)attn3f, 512, (long)PSTR * 512, NTOK, w2bt, 256, 16384,
            aout, nullptr, 512, 64, NTOK, 256, 1);
        k_cvt_pad<<<dim3((MOUT * DIM + 255) / 256), 256, 0, stream>>>(aout, abf, NTOK, MOUT, DIM);
        k_mfma_gemm<<<dim3(4, 79), 256, 0, stream>>>(abf, owt, h, MOUT, 512, 512,
                                                     NTOK, 0, 0.f, outb, 1, nullptr);
    };

    layer(ln1w, ln1b, qw1t, ow1t, out1b, res1w);

    k_tfwd<<<dim3(313, 16), 256, 0, stream>>>(h, ft);
    k_ppeg2<<<dim3(5, 512), 256, 0, stream>>>(ft, yt, p7w, p7b, p5w, p5b, p3w, p3b);
    k_tback<<<dim3(313, 16), 256, 0, stream>>>(yt, h);

    layer(ln2w, ln2b, qw2t, ow2t, out2b, res2w);

    k_final<<<NTOK, 256, 0, stream>>>(h, normw, normb, fc2w, fc2b, pcw, pcb, out);
    (void)in_sizes; (void)n_in; (void)out_size; (void)ws_size;
}